// Round 1
// baseline (265.539 us; speedup 1.0000x reference)
//
#include <hip/hip_runtime.h>
#include <hip/hip_bf16.h>
#include <math.h>

#define BT 48
#define N 1024
#define F 64
#define CIN 64
#define EM 16
#define LRELU_ALPHA 0.2f
#define NEG_INF_V -9e15f
#define ROWS 8

// ------------------------------------------------------------------
// Kernel 1: Wh = x @ W  (rows = bt*N flat), plus s1 = Wh.a[:64],
// s2 = Wh.a[64:] fused as wave reductions (wave == one row's 64 f lanes).
// ------------------------------------------------------------------
__global__ __launch_bounds__(256) void k_project(
    const float* __restrict__ x, const float* __restrict__ W,
    const float* __restrict__ a,
    float* __restrict__ Wh, float* __restrict__ s1, float* __restrict__ s2)
{
    __shared__ float sW[CIN * F];     // 16 KiB
    __shared__ float sx[4 * CIN];     // 1 KiB (4 rows per block)
    const int tid = threadIdx.x;
    for (int i = tid; i < CIN * F; i += 256) sW[i] = W[i];
    const int rowbase = blockIdx.x * 4;
    sx[tid] = x[(size_t)rowbase * CIN + tid];   // 256 contiguous floats
    __syncthreads();

    const int r = tid >> 6;      // wave id = row within block
    const int f = tid & 63;      // lane = output feature
    float acc = 0.f;
#pragma unroll
    for (int c = 0; c < CIN; ++c)
        acc = fmaf(sx[r * CIN + c], sW[c * F + f], acc);   // sx broadcast, sW 2-way (free)

    const int row = rowbase + r;
    Wh[(size_t)row * F + f] = acc;

    float v1 = acc * a[f];
    float v2 = acc * a[F + f];
#pragma unroll
    for (int off = 32; off >= 1; off >>= 1) {
        v1 += __shfl_xor(v1, off, 64);
        v2 += __shfl_xor(v2, off, 64);
    }
    if (f == 0) { s1[row] = v1; s2[row] = v2; }
}

// ------------------------------------------------------------------
// Kernel 2: f1[n] = emb1[n,:].a2[:16], f2[n] = emb2[n,:].a2[16:]
// ------------------------------------------------------------------
__global__ __launch_bounds__(256) void k_embed(
    const float* __restrict__ emb1, const float* __restrict__ emb2,
    const float* __restrict__ a2,
    float* __restrict__ f1, float* __restrict__ f2)
{
    const int n = blockIdx.x * 256 + threadIdx.x;
    if (n < N) {
        float v1 = 0.f, v2 = 0.f;
#pragma unroll
        for (int k = 0; k < EM; ++k) {
            v1 = fmaf(emb1[n * EM + k], a2[k], v1);
            v2 = fmaf(emb2[n * EM + k], a2[EM + k], v2);
        }
        f1[n] = v1; f2[n] = v2;
    }
}

// ------------------------------------------------------------------
// Kernel 3: per (bt, 8-row tile): e = lrelu(r_i + c_j), mask by adj,
// row softmax, h = att @ Wh, elu, store.
// ------------------------------------------------------------------
__global__ __launch_bounds__(256) void k_attn(
    const int*   __restrict__ adj,
    const float* __restrict__ Wh,
    const float* __restrict__ s1, const float* __restrict__ s2,
    const float* __restrict__ f1v, const float* __restrict__ f2v,
    float* __restrict__ out)
{
    __shared__ __align__(16) float sE[ROWS * N];  // 32 KiB: e, then p in place, then reduce scratch
    __shared__ float sC[N];                       // 4 KiB: c_j = s2[j] + f2[j]
    __shared__ float sR[ROWS];                    // r_i = s1[i] + f1[i]
    __shared__ float sL[ROWS];                    // softmax denominators

    const int tid  = threadIdx.x;
    const int bt   = blockIdx.x >> 7;        // 128 tiles per bt
    const int tile = blockIdx.x & 127;
    const int i0   = tile * ROWS;

    for (int j = tid; j < N; j += 256) sC[j] = s2[bt * N + j] + f2v[j];
    if (tid < ROWS) sR[tid] = s1[bt * N + i0 + tid] + f1v[i0 + tid];
    __syncthreads();

    // Phase 1: masked leaky-relu scores, coalesced adj reads
    for (int idx = tid; idx < ROWS * N; idx += 256) {
        const int r = idx >> 10, j = idx & (N - 1);
        float e = sR[r] + sC[j];
        e = e > 0.f ? e : LRELU_ALPHA * e;
        sE[idx] = (adj[(size_t)(i0 + r) * N + j] > 0) ? e : NEG_INF_V;
    }
    __syncthreads();

    // Phase 2: per-wave softmax; wave w owns rows {w, w+4}; p overwrites e in place
    const int lane = tid & 63, w = tid >> 6;
    for (int rr = w; rr < ROWS; rr += 4) {
        const int base = rr * N;
        float m = -INFINITY;
#pragma unroll
        for (int t = 0; t < 16; ++t) m = fmaxf(m, sE[base + lane + 64 * t]);
#pragma unroll
        for (int off = 32; off >= 1; off >>= 1) m = fmaxf(m, __shfl_xor(m, off, 64));
        float l = 0.f;
#pragma unroll
        for (int t = 0; t < 16; ++t) {
            const int jj = base + lane + 64 * t;
            const float p = __expf(sE[jj] - m);
            l += p;
            sE[jj] = p;    // same lane rereads/writes only its own addresses: safe
        }
#pragma unroll
        for (int off = 32; off >= 1; off >>= 1) l += __shfl_xor(l, off, 64);
        if (lane == 0) sL[rr] = l;
    }
    __syncthreads();

    // Phase 3: acc[r][f] += p[r][j] * Wh[j][f]; f = lane, 4 j-groups of 256
    const int f = tid & 63, g = tid >> 6;
    float acc[ROWS];
#pragma unroll
    for (int r = 0; r < ROWS; ++r) acc[r] = 0.f;
    const float* WhB = Wh + (size_t)bt * N * F;
    const int jend = g * 256 + 256;
    for (int jb = g * 256; jb < jend; jb += 4) {
        const float wh0 = WhB[(jb + 0) * F + f];   // coalesced 256B/wave, L2-resident
        const float wh1 = WhB[(jb + 1) * F + f];
        const float wh2 = WhB[(jb + 2) * F + f];
        const float wh3 = WhB[(jb + 3) * F + f];
#pragma unroll
        for (int r = 0; r < ROWS; ++r) {
            const float4 p4 = *(const float4*)&sE[r * N + jb];  // wave-uniform broadcast
            acc[r] = fmaf(p4.x, wh0, acc[r]);
            acc[r] = fmaf(p4.y, wh1, acc[r]);
            acc[r] = fmaf(p4.z, wh2, acc[r]);
            acc[r] = fmaf(p4.w, wh3, acc[r]);
        }
    }
    __syncthreads();   // everyone done reading p before sE is reused as scratch

    // Cross-group reduction via sE scratch: [g][r][f]
#pragma unroll
    for (int r = 0; r < ROWS; ++r) sE[g * (ROWS * F) + r * F + f] = acc[r];
    __syncthreads();

#pragma unroll
    for (int it = 0; it < 2; ++it) {
        const int oi = tid + it * 256;       // 512 outputs (8 rows x 64 f)
        const int r = oi >> 6, ff = oi & 63;
        float h = sE[0 * (ROWS * F) + r * F + ff]
                + sE[1 * (ROWS * F) + r * F + ff]
                + sE[2 * (ROWS * F) + r * F + ff]
                + sE[3 * (ROWS * F) + r * F + ff];
        h /= sL[r];
        h = h > 0.f ? h : (__expf(h) - 1.f);   // ELU (alpha=1)
        out[(size_t)(bt * N + i0 + r) * F + ff] = h;
    }
}

// ------------------------------------------------------------------
extern "C" void kernel_launch(void* const* d_in, const int* in_sizes, int n_in,
                              void* d_out, int out_size, void* d_ws, size_t ws_size,
                              hipStream_t stream)
{
    const float* x    = (const float*)d_in[0];
    const int*   adj  = (const int*)  d_in[1];
    const float* emb1 = (const float*)d_in[2];
    const float* emb2 = (const float*)d_in[3];
    const float* W    = (const float*)d_in[4];
    const float* a    = (const float*)d_in[5];
    const float* a2   = (const float*)d_in[6];
    float* out = (float*)d_out;

    float* ws = (float*)d_ws;
    float* Wh = ws;                                   // BT*N*F
    float* s1 = Wh + (size_t)BT * N * F;              // BT*N
    float* s2 = s1 + BT * N;                          // BT*N
    float* f1 = s2 + BT * N;                          // N
    float* f2 = f1 + N;                               // N

    hipLaunchKernelGGL(k_project, dim3(BT * N / 4), dim3(256), 0, stream,
                       x, W, a, Wh, s1, s2);
    hipLaunchKernelGGL(k_embed, dim3(N / 256), dim3(256), 0, stream,
                       emb1, emb2, a2, f1, f2);
    hipLaunchKernelGGL(k_attn, dim3(BT * (N / ROWS)), dim3(256), 0, stream,
                       adj, Wh, s1, s2, f1, f2, out);
}

// Round 2
// 147.858 us; speedup vs baseline: 1.7959x; 1.7959x over previous
//
#include <hip/hip_runtime.h>
#include <hip/hip_bf16.h>
#include <math.h>

#define BT 48
#define N 1024
#define F 64
#define CIN 64
#define EM 16
#define LRELU_A 0.2f
#define KC 128
#define SPITCH 136   // bf16 elements per sP row: 128 + 8 pad -> 272B pitch, 16B-aligned

typedef short  bf16x8  __attribute__((ext_vector_type(8)));   // 8 bf16 = 4 VGPRs (guide §3)
typedef float  f32x16  __attribute__((ext_vector_type(16)));

// exact RTNE float->bf16 bits (no NaN handling needed here)
__device__ __forceinline__ unsigned short f2bf(float f) {
    unsigned int u = __float_as_uint(f);
    unsigned int r = (u + 0x7FFFu + ((u >> 16) & 1u)) >> 16;
    return (unsigned short)r;
}

// ------------------------------------------------------------------
// k_project: 64 rows per block (768 blocks). Computes Wh row-block in f32,
// writes WhbT (bf16, [bt*64+f][n] i.e. feature-major TRANSPOSED for MFMA
// B-fragments), and s1/s2 via wave shuffle reductions.
// ------------------------------------------------------------------
__global__ __launch_bounds__(256) void k_project(
    const float* __restrict__ x, const float* __restrict__ W,
    const float* __restrict__ a,
    unsigned short* __restrict__ WhbT,
    float* __restrict__ s1, float* __restrict__ s2)
{
    __shared__ __align__(16) float sx[64 * 64];          // [r][c]
    __shared__ __align__(16) float sWT[64 * 68];         // [f][c] pitch 68 (4-pass b128, no conflict)
    __shared__ unsigned short sT[64 * 72];               // [f][r] pitch 72

    const int tid = threadIdx.x;
    const int bt  = blockIdx.x >> 4;
    const int n0  = (blockIdx.x & 15) * 64;              // row base within bt
    const size_t grow = (size_t)bt * N + n0;             // global flat row base

    // stage x rows (coalesced float4) and W transposed
    {
        const float4* xv = (const float4*)(x + grow * CIN);
        float4* sxv = (float4*)sx;
        for (int i = tid; i < 64 * CIN / 4; i += 256) sxv[i] = xv[i];
        for (int i = tid; i < CIN * F; i += 256)
            sWT[(i & 63) * 68 + (i >> 6)] = W[i];        // W[c][f] -> sWT[f][c]
    }
    __syncthreads();

    const int f = tid & 63;
    const int w = tid >> 6;                              // wave: rows w*16..w*16+15
    const float a1 = a[f], a2c = a[F + f];

    float acc[16];
#pragma unroll
    for (int t = 0; t < 16; ++t) acc[t] = 0.f;

    for (int cb = 0; cb < CIN; cb += 4) {
        const float4 wv = *(const float4*)&sWT[f * 68 + cb];
#pragma unroll
        for (int t = 0; t < 16; ++t) {
            const float4 xv = *(const float4*)&sx[(w * 16 + t) * 64 + cb]; // wave-uniform broadcast
            acc[t] = fmaf(xv.x, wv.x, acc[t]);
            acc[t] = fmaf(xv.y, wv.y, acc[t]);
            acc[t] = fmaf(xv.z, wv.z, acc[t]);
            acc[t] = fmaf(xv.w, wv.w, acc[t]);
        }
    }

    // s1/s2: per-row wave reductions over the 64 f-lanes
#pragma unroll
    for (int t = 0; t < 16; ++t) {
        float v1 = acc[t] * a1;
        float v2 = acc[t] * a2c;
#pragma unroll
        for (int off = 32; off >= 1; off >>= 1) {
            v1 += __shfl_xor(v1, off, 64);
            v2 += __shfl_xor(v2, off, 64);
        }
        if (f == 0) {
            s1[grow + w * 16 + t] = v1;
            s2[grow + w * 16 + t] = v2;
        }
        // transpose through LDS: sT[f][row]
        sT[f * 72 + w * 16 + t] = f2bf(acc[t]);
    }
    __syncthreads();

    // write WhbT[(bt*64+f)*1024 + n0 + r], coalesced uint (2 bf16) stores
    for (int i = tid; i < 2048; i += 256) {
        const int ff = i >> 5, r2 = (i & 31) * 2;
        *(unsigned int*)&WhbT[((size_t)(bt * 64 + ff)) * N + n0 + r2] =
            *(const unsigned int*)&sT[ff * 72 + r2];
    }
}

// ------------------------------------------------------------------
// k_embed: f1[n] = emb1[n,:].a2[:16], f2[n] = emb2[n,:].a2[16:]
// ------------------------------------------------------------------
__global__ __launch_bounds__(256) void k_embed(
    const float* __restrict__ emb1, const float* __restrict__ emb2,
    const float* __restrict__ a2,
    float* __restrict__ f1, float* __restrict__ f2)
{
    const int n = blockIdx.x * 256 + threadIdx.x;
    if (n < N) {
        float v1 = 0.f, v2 = 0.f;
#pragma unroll
        for (int k = 0; k < EM; ++k) {
            v1 = fmaf(emb1[n * EM + k], a2[k], v1);
            v2 = fmaf(emb2[n * EM + k], a2[EM + k], v2);
        }
        f1[n] = v1; f2[n] = v2;
    }
}

// ------------------------------------------------------------------
// k_attn: per block (bt, 64 query rows). Single pass over adj:
//   p~ = exp(lrelu(r_i+c_j) - m^_i) masked, bf16 into LDS (A-layout),
//   MFMA 32x32x16 against WhbT B-fragments, normalize by sum(p~) at end.
// m^_i = lrelu(r_i + maxC) >= row max (lrelu monotone) -> exp <= 1, no max pass.
// ------------------------------------------------------------------
__global__ __launch_bounds__(256) void k_attn(
    const int* __restrict__ adj,
    const unsigned short* __restrict__ WhbT,
    const float* __restrict__ s1, const float* __restrict__ s2,
    const float* __restrict__ f1v, const float* __restrict__ f2v,
    float* __restrict__ out)
{
    __shared__ __align__(16) float sC[N];                 // c_j = s2+f2
    __shared__ float sR[64];                              // r_i = s1+f1
    __shared__ __align__(16) unsigned short sP[64 * SPITCH]; // p~ chunk, bf16
    __shared__ float sL[64];                              // softmax denominators
    __shared__ float sWmax[4];

    const int tid = threadIdx.x;
    const int bt  = blockIdx.x >> 4;
    const int i0  = (blockIdx.x & 15) * 64;

    // Phase 0: sC, sR, block max of c
    float lmax = -1e30f;
    for (int j = tid; j < N; j += 256) {
        const float c = s2[bt * N + j] + f2v[j];
        sC[j] = c;
        lmax = fmaxf(lmax, c);
    }
    if (tid < 64) sR[tid] = s1[bt * N + i0 + tid] + f1v[i0 + tid];
#pragma unroll
    for (int off = 32; off >= 1; off >>= 1) lmax = fmaxf(lmax, __shfl_xor(lmax, off, 64));
    if ((tid & 63) == 0) sWmax[tid >> 6] = lmax;
    __syncthreads();
    const float maxC = fmaxf(fmaxf(sWmax[0], sWmax[1]), fmaxf(sWmax[2], sWmax[3]));

    const int lane = tid & 63;
    const int w    = tid >> 6;
    const int wm   = w >> 1, wn = w & 1;       // 2x2 wave grid over 64x64 output
    const int hi8  = (lane >> 5) * 8;
    const int Arow = wm * 32 + (lane & 31);
    const unsigned short* Bptr = WhbT + ((size_t)(bt * 64 + wn * 32 + (lane & 31))) * N;

    // per-wave softmax rows: w*16 .. w*16+15
    float rowR[16], rowM[16], lsum[16];
#pragma unroll
    for (int t = 0; t < 16; ++t) {
        const float r = sR[w * 16 + t];
        rowR[t] = r;
        const float s = r + maxC;
        rowM[t] = (s > 0.f) ? s : LRELU_A * s;   // m^ >= every e in the row
        lsum[t] = 0.f;
    }

    f32x16 accf;
#pragma unroll
    for (int q = 0; q < 16; ++q) accf[q] = 0.f;

    for (int k0 = 0; k0 < N; k0 += KC) {
        // prefetch B fragments for this chunk (independent of the barrier)
        bf16x8 bv[KC / 16];
#pragma unroll
        for (int ks = 0; ks < KC / 16; ++ks)
            bv[ks] = *(const bf16x8*)&Bptr[k0 + ks * 16 + hi8];

        // score/softmax chunk: rows w*16+t, cols k0 + u*64 + lane
#pragma unroll
        for (int u = 0; u < 2; ++u) {
            const int j  = k0 + u * 64 + lane;
            const float cj = sC[j];
#pragma unroll
            for (int t = 0; t < 16; ++t) {
                const int av = adj[(i0 + w * 16 + t) * N + j];   // coalesced, L2-resident
                const float s = rowR[t] + cj;
                const float e = (s > 0.f) ? s : LRELU_A * s;
                float p = __expf(e - rowM[t]);                   // <= 1 always
                p = (av > 0) ? p : 0.f;
                lsum[t] += p;
                sP[(w * 16 + t) * SPITCH + u * 64 + lane] = f2bf(p);
            }
        }
        __syncthreads();

        // MFMA over the chunk: A from sP (LDS), B prefetched
#pragma unroll
        for (int ks = 0; ks < KC / 16; ++ks) {
            const bf16x8 avf = *(const bf16x8*)&sP[Arow * SPITCH + ks * 16 + hi8];
            accf = __builtin_amdgcn_mfma_f32_32x32x16_bf16(avf, bv[ks], accf, 0, 0, 0);
        }
        __syncthreads();
    }

    // denominators
#pragma unroll
    for (int t = 0; t < 16; ++t) {
        float l = lsum[t];
#pragma unroll
        for (int off = 32; off >= 1; off >>= 1) l += __shfl_xor(l, off, 64);
        if (lane == 0) sL[w * 16 + t] = l;
    }
    __syncthreads();

    // epilogue: C/D layout col=lane&31, row=(reg&3)+8*(reg>>2)+4*(lane>>5)
    const int ocol = wn * 32 + (lane & 31);
#pragma unroll
    for (int reg = 0; reg < 16; ++reg) {
        const int orow = wm * 32 + (reg & 3) + 8 * (reg >> 2) + 4 * (lane >> 5);
        float h = accf[reg] / sL[orow];
        h = (h > 0.f) ? h : (__expf(h) - 1.f);                   // ELU
        out[((size_t)(bt * N) + i0 + orow) * F + ocol] = h;
    }
}

// ------------------------------------------------------------------
extern "C" void kernel_launch(void* const* d_in, const int* in_sizes, int n_in,
                              void* d_out, int out_size, void* d_ws, size_t ws_size,
                              hipStream_t stream)
{
    const float* x    = (const float*)d_in[0];
    const int*   adj  = (const int*)  d_in[1];
    const float* emb1 = (const float*)d_in[2];
    const float* emb2 = (const float*)d_in[3];
    const float* W    = (const float*)d_in[4];
    const float* a    = (const float*)d_in[5];
    const float* a2   = (const float*)d_in[6];
    float* out = (float*)d_out;

    unsigned short* WhbT = (unsigned short*)d_ws;          // BT*64*1024 bf16
    float* s1 = (float*)(WhbT + (size_t)BT * F * N);       // BT*N
    float* s2 = s1 + BT * N;
    float* f1 = s2 + BT * N;
    float* f2 = f1 + N;

    hipLaunchKernelGGL(k_project, dim3(BT * 16), dim3(256), 0, stream,
                       x, W, a, WhbT, s1, s2);
    hipLaunchKernelGGL(k_embed, dim3((N + 255) / 256), dim3(256), 0, stream,
                       emb1, emb2, a2, f1, f2);
    hipLaunchKernelGGL(k_attn, dim3(BT * 16), dim3(256), 0, stream,
                       adj, WhbT, s1, s2, f1, f2, out);
}

// Round 3
// 144.849 us; speedup vs baseline: 1.8332x; 1.0208x over previous
//
#include <hip/hip_runtime.h>
#include <hip/hip_bf16.h>
#include <math.h>

#define BT 48
#define N 1024
#define F 64
#define CIN 64
#define EM 16
#define LRELU_A 0.2f

typedef short bf16x8 __attribute__((ext_vector_type(8)));   // 8 bf16 = 4 VGPRs
typedef float f32x4  __attribute__((ext_vector_type(4)));

// exact RTNE float->bf16 bits
__device__ __forceinline__ unsigned short f2bf(float f) {
    unsigned int u = __float_as_uint(f);
    return (unsigned short)((u + 0x7FFFu + ((u >> 16) & 1u)) >> 16);
}

// ------------------------------------------------------------------
// k_project: 64 rows/block (768 blocks). Wh row-block in f32 -> WhbT
// (bf16, feature-major [bt*64+f][n] for MFMA B-frags) + s1/s2 via
// wave shuffle reductions. (Unchanged from round 2 — works.)
// ------------------------------------------------------------------
__global__ __launch_bounds__(256) void k_project(
    const float* __restrict__ x, const float* __restrict__ W,
    const float* __restrict__ a,
    unsigned short* __restrict__ WhbT,
    float* __restrict__ s1, float* __restrict__ s2)
{
    __shared__ __align__(16) float sx[64 * 64];
    __shared__ __align__(16) float sWT[64 * 68];
    __shared__ unsigned short sT[64 * 72];

    const int tid = threadIdx.x;
    const int bt  = blockIdx.x >> 4;
    const int n0  = (blockIdx.x & 15) * 64;
    const size_t grow = (size_t)bt * N + n0;

    {
        const float4* xv = (const float4*)(x + grow * CIN);
        float4* sxv = (float4*)sx;
        for (int i = tid; i < 64 * CIN / 4; i += 256) sxv[i] = xv[i];
        for (int i = tid; i < CIN * F; i += 256)
            sWT[(i & 63) * 68 + (i >> 6)] = W[i];
    }
    __syncthreads();

    const int f = tid & 63;
    const int w = tid >> 6;
    const float a1 = a[f], a2c = a[F + f];

    float acc[16];
#pragma unroll
    for (int t = 0; t < 16; ++t) acc[t] = 0.f;

    for (int cb = 0; cb < CIN; cb += 4) {
        const float4 wv = *(const float4*)&sWT[f * 68 + cb];
#pragma unroll
        for (int t = 0; t < 16; ++t) {
            const float4 xv = *(const float4*)&sx[(w * 16 + t) * 64 + cb];
            acc[t] = fmaf(xv.x, wv.x, acc[t]);
            acc[t] = fmaf(xv.y, wv.y, acc[t]);
            acc[t] = fmaf(xv.z, wv.z, acc[t]);
            acc[t] = fmaf(xv.w, wv.w, acc[t]);
        }
    }

#pragma unroll
    for (int t = 0; t < 16; ++t) {
        float v1 = acc[t] * a1;
        float v2 = acc[t] * a2c;
#pragma unroll
        for (int off = 32; off >= 1; off >>= 1) {
            v1 += __shfl_xor(v1, off, 64);
            v2 += __shfl_xor(v2, off, 64);
        }
        if (f == 0) {
            s1[grow + w * 16 + t] = v1;
            s2[grow + w * 16 + t] = v2;
        }
        sT[f * 72 + w * 16 + t] = f2bf(acc[t]);
    }
    __syncthreads();

    for (int i = tid; i < 2048; i += 256) {
        const int ff = i >> 5, r2 = (i & 31) * 2;
        *(unsigned int*)&WhbT[((size_t)(bt * 64 + ff)) * N + n0 + r2] =
            *(const unsigned int*)&sT[ff * 72 + r2];
    }
}

// ------------------------------------------------------------------
// k_misc: blocks 0..127 pack adj -> bitmask (1024 x 32 uint32);
//         blocks 128..131 compute f1/f2 embedding scores.
// ------------------------------------------------------------------
__global__ __launch_bounds__(256) void k_misc(
    const int* __restrict__ adj,
    const float* __restrict__ emb1, const float* __restrict__ emb2,
    const float* __restrict__ a2,
    unsigned int* __restrict__ adjBits,
    float* __restrict__ f1, float* __restrict__ f2)
{
    const int b = blockIdx.x;
    if (b < 128) {
        const int idx = b * 256 + threadIdx.x;          // word index
        const int r = idx >> 5, w32 = idx & 31;
        const int* p = adj + (size_t)r * N + w32 * 32;
        unsigned int m = 0;
#pragma unroll
        for (int j = 0; j < 32; ++j) m |= (p[j] > 0 ? 1u : 0u) << j;
        adjBits[idx] = m;
    } else {
        const int n = (b - 128) * 256 + threadIdx.x;
        if (n < N) {
            float v1 = 0.f, v2 = 0.f;
#pragma unroll
            for (int k = 0; k < EM; ++k) {
                v1 = fmaf(emb1[n * EM + k], a2[k], v1);
                v2 = fmaf(emb2[n * EM + k], a2[EM + k], v2);
            }
            f1[n] = v1; f2[n] = v2;
        }
    }
}

// ------------------------------------------------------------------
// k_attn: barrier-free K-loop. Wave w owns rows w*16..w*16+15 (16x16x32
// MFMA, 4 col-tiles). A fragments (p~ bf16) built directly in registers
// in A-layout A[m=lane&15][k=(lane>>4)*8+j]; adj mask from packed bits
// (1 uint4/lane/chunk); B frags prefetched before exp-heavy score gen.
// m^_i = lrelu(r_i + maxC) >= row max (lrelu monotone): single pass.
// ------------------------------------------------------------------
__global__ __launch_bounds__(256, 3) void k_attn(
    const unsigned int* __restrict__ adjBits,
    const unsigned short* __restrict__ WhbT,
    const float* __restrict__ s1, const float* __restrict__ s2,
    const float* __restrict__ f1v, const float* __restrict__ f2v,
    float* __restrict__ out)
{
    __shared__ __align__(16) float sC[N];

    const int tid  = threadIdx.x;
    const int bt   = blockIdx.x >> 4;
    const int i0   = (blockIdx.x & 15) * 64;
    const int lane = tid & 63;
    const int w    = tid >> 6;
    const int q    = lane >> 4;        // k-quad
    const int m15  = lane & 15;        // A row / out col within tile

    // stage c_j = s2 + f2 (the only shared state; single barrier)
    for (int j = tid; j < N; j += 256) sC[j] = s2[bt * N + j] + f2v[j];
    __syncthreads();

    // per-wave max over all c (for the m^ bound)
    float mx = -1e30f;
#pragma unroll
    for (int t = 0; t < 4; ++t) {
        const float4 v = *(const float4*)&sC[lane * 16 + t * 4];
        mx = fmaxf(mx, fmaxf(fmaxf(v.x, v.y), fmaxf(v.z, v.w)));
    }
#pragma unroll
    for (int off = 32; off >= 1; off >>= 1) mx = fmaxf(mx, __shfl_xor(mx, off, 64));

    // this lane's query row
    const int growq = i0 + w * 16 + m15;
    const float r   = s1[bt * N + growq] + f1v[growq];
    const float sm  = r + mx;
    const float mhat = (sm > 0.f) ? sm : LRELU_A * sm;   // >= every e in row
    float lsum = 0.f;

    const unsigned int*   abRow = adjBits + growq * 32;
    const unsigned short* Bbase = WhbT + (size_t)(bt * 64 + m15) * N;

    f32x4 acc[4];
#pragma unroll
    for (int ct = 0; ct < 4; ++ct)
#pragma unroll
        for (int e = 0; e < 4; ++e) acc[ct][e] = 0.f;

    for (int ch = 0; ch < 8; ++ch) {
        const int k0 = ch * 128;

        // adjacency bits for this row, cols k0..k0+127
        const uint4 ab = *(const uint4*)&abRow[ch * 4];
        const unsigned int abw[4] = {ab.x, ab.y, ab.z, ab.w};

        // prefetch all 16 B fragments (latency hidden behind score gen)
        bf16x8 bfr[16];
#pragma unroll
        for (int ct = 0; ct < 4; ++ct)
#pragma unroll
            for (int ks = 0; ks < 4; ++ks)
                bfr[ct * 4 + ks] =
                    *(const bf16x8*)&Bbase[(size_t)ct * 16 * N + k0 + ks * 32 + q * 8];

        // A fragments: p~ for (row m15, k = ks*32 + q*8 + j), in-register
        bf16x8 afr[4];
#pragma unroll
        for (int ks = 0; ks < 4; ++ks) {
            const float4 c0 = *(const float4*)&sC[k0 + ks * 32 + q * 8];
            const float4 c1 = *(const float4*)&sC[k0 + ks * 32 + q * 8 + 4];
            const float cj[8] = {c0.x, c0.y, c0.z, c0.w, c1.x, c1.y, c1.z, c1.w};
            const unsigned int mb = (abw[ks] >> (q * 8)) & 0xFFu;
            bf16x8 av;
#pragma unroll
            for (int j = 0; j < 8; ++j) {
                const float s = r + cj[j];
                const float e = (s > 0.f) ? s : LRELU_A * s;
                float p = __expf(e - mhat);                  // <= 1 always
                p = ((mb >> j) & 1u) ? p : 0.f;
                lsum += p;
                av[j] = (short)f2bf(p);
            }
            afr[ks] = av;
        }

        // MFMA: no barrier anywhere in this loop
#pragma unroll
        for (int ct = 0; ct < 4; ++ct)
#pragma unroll
            for (int ks = 0; ks < 4; ++ks)
                acc[ct] = __builtin_amdgcn_mfma_f32_16x16x32_bf16(
                    afr[ks], bfr[ct * 4 + ks], acc[ct], 0, 0, 0);
    }

    // row denominators: lanes {l, l^16, l^32, l^48} share a row
    lsum += __shfl_xor(lsum, 16, 64);
    lsum += __shfl_xor(lsum, 32, 64);

    // reciprocal for the 4 output rows this lane writes (C/D row = q*4+reg)
    float rinv[4];
#pragma unroll
    for (int reg = 0; reg < 4; ++reg)
        rinv[reg] = 1.f / __shfl(lsum, q * 4 + reg, 64);

#pragma unroll
    for (int ct = 0; ct < 4; ++ct) {
#pragma unroll
        for (int reg = 0; reg < 4; ++reg) {
            float h = acc[ct][reg] * rinv[reg];
            h = (h > 0.f) ? h : (__expf(h) - 1.f);           // ELU
            out[(size_t)(bt * N + i0 + w * 16 + q * 4 + reg) * F + ct * 16 + m15] = h;
        }
    }
}

// ------------------------------------------------------------------
extern "C" void kernel_launch(void* const* d_in, const int* in_sizes, int n_in,
                              void* d_out, int out_size, void* d_ws, size_t ws_size,
                              hipStream_t stream)
{
    const float* x    = (const float*)d_in[0];
    const int*   adj  = (const int*)  d_in[1];
    const float* emb1 = (const float*)d_in[2];
    const float* emb2 = (const float*)d_in[3];
    const float* W    = (const float*)d_in[4];
    const float* a    = (const float*)d_in[5];
    const float* a2   = (const float*)d_in[6];
    float* out = (float*)d_out;

    unsigned short* WhbT = (unsigned short*)d_ws;             // 48*64*1024 bf16 = 6.29 MB
    float* s1 = (float*)(WhbT + (size_t)BT * F * N);          // 48K f32
    float* s2 = s1 + BT * N;                                  // 48K f32
    float* f1 = s2 + BT * N;                                  // 1K
    float* f2 = f1 + N;                                       // 1K
    unsigned int* adjBits = (unsigned int*)(f2 + N);          // 32K uint = 128 KB

    hipLaunchKernelGGL(k_project, dim3(BT * 16), dim3(256), 0, stream,
                       x, W, a, WhbT, s1, s2);
    hipLaunchKernelGGL(k_misc, dim3(132), dim3(256), 0, stream,
                       adj, emb1, emb2, a2, adjBits, f1, f2);
    hipLaunchKernelGGL(k_attn, dim3(BT * 16), dim3(256), 0, stream,
                       adjBits, WhbT, s1, s2, f1, f2, out);
}

// Round 4
// 124.109 us; speedup vs baseline: 2.1396x; 1.1671x over previous
//
#include <hip/hip_runtime.h>
#include <hip/hip_bf16.h>
#include <math.h>

#define BT 48
#define N 1024
#define F 64
#define CIN 64
#define EM 16
#define LRELU_A 0.2f

typedef short bf16x8 __attribute__((ext_vector_type(8)));   // 8 bf16 = 4 VGPRs
typedef float f32x4  __attribute__((ext_vector_type(4)));

// exact RTNE float->bf16 bits (used in k_project, off the hot path)
__device__ __forceinline__ unsigned short f2bf(float f) {
    unsigned int u = __float_as_uint(f);
    return (unsigned short)((u + 0x7FFFu + ((u >> 16) & 1u)) >> 16);
}

// ------------------------------------------------------------------
// k_proj_misc: blocks 0..767   : Wh row-block (64 rows) -> WhSw swizzled
//                                bf16 [bt][nb32][f][q][j] + s1/s2
//              blocks 768..895 : pack adj -> bitmask
//              blocks 896..899 : f1/f2 embedding scores
// ------------------------------------------------------------------
__global__ __launch_bounds__(256) void k_proj_misc(
    const float* __restrict__ x, const float* __restrict__ W,
    const float* __restrict__ a,
    const int* __restrict__ adj,
    const float* __restrict__ emb1, const float* __restrict__ emb2,
    const float* __restrict__ a2,
    unsigned short* __restrict__ WhSw,
    float* __restrict__ s1, float* __restrict__ s2,
    unsigned int* __restrict__ adjBits,
    float* __restrict__ f1, float* __restrict__ f2)
{
    const int tid = threadIdx.x;
    const int b   = blockIdx.x;

    if (b >= 768) {
        if (b < 896) {                       // adj bit-pack: 1024x32 words
            const int idx = (b - 768) * 256 + tid;
            const int r = idx >> 5, w32 = idx & 31;
            const int* p = adj + (size_t)r * N + w32 * 32;
            unsigned int m = 0;
#pragma unroll
            for (int j = 0; j < 32; ++j) m |= (p[j] > 0 ? 1u : 0u) << j;
            adjBits[idx] = m;
        } else {                             // embedding scores
            const int n = (b - 896) * 256 + tid;
            if (n < N) {
                float v1 = 0.f, v2 = 0.f;
#pragma unroll
                for (int k = 0; k < EM; ++k) {
                    v1 = fmaf(emb1[n * EM + k], a2[k], v1);
                    v2 = fmaf(emb2[n * EM + k], a2[EM + k], v2);
                }
                f1[n] = v1; f2[n] = v2;
            }
        }
        return;
    }

    __shared__ __align__(16) float sx[64 * 64];           // [r][c]
    __shared__ __align__(16) float sWT[64 * 68];          // [f][c] pitch 68
    __shared__ __align__(16) unsigned short sT[64 * 80];  // [f][r] pitch 80 (16B-aligned b128 rows)

    const int bt  = b >> 4;
    const int n0  = (b & 15) * 64;
    const size_t grow = (size_t)bt * N + n0;

    {
        const float4* xv = (const float4*)(x + grow * CIN);
        float4* sxv = (float4*)sx;
        for (int i = tid; i < 64 * CIN / 4; i += 256) sxv[i] = xv[i];
        for (int i = tid; i < CIN * F; i += 256)
            sWT[(i & 63) * 68 + (i >> 6)] = W[i];         // W[c][f] -> sWT[f][c]
    }
    __syncthreads();

    const int f = tid & 63;
    const int w = tid >> 6;                               // wave: rows w*16..w*16+15
    const float a1 = a[f], a2c = a[F + f];

    float acc[16];
#pragma unroll
    for (int t = 0; t < 16; ++t) acc[t] = 0.f;

    for (int cb = 0; cb < CIN; cb += 4) {
        const float4 wv = *(const float4*)&sWT[f * 68 + cb];
#pragma unroll
        for (int t = 0; t < 16; ++t) {
            const float4 xv = *(const float4*)&sx[(w * 16 + t) * 64 + cb];  // broadcast
            acc[t] = fmaf(xv.x, wv.x, acc[t]);
            acc[t] = fmaf(xv.y, wv.y, acc[t]);
            acc[t] = fmaf(xv.z, wv.z, acc[t]);
            acc[t] = fmaf(xv.w, wv.w, acc[t]);
        }
    }

#pragma unroll
    for (int t = 0; t < 16; ++t) {
        float v1 = acc[t] * a1;
        float v2 = acc[t] * a2c;
#pragma unroll
        for (int off = 32; off >= 1; off >>= 1) {
            v1 += __shfl_xor(v1, off, 64);
            v2 += __shfl_xor(v2, off, 64);
        }
        if (f == 0) {
            s1[grow + w * 16 + t] = v1;
            s2[grow + w * 16 + t] = v2;
        }
        sT[f * 80 + w * 16 + t] = f2bf(acc[t]);           // transpose via LDS
    }
    __syncthreads();

    // WhSw[(bt*32+nb)*64 + f][q][j]: 16B per thread per nb, coalesced
    {
        const int ff = tid >> 2, q = tid & 3;
        const int nb0 = (b & 15) * 2;
#pragma unroll
        for (int nbL = 0; nbL < 2; ++nbL) {
            const size_t dst = ((size_t)(bt * 32 + nb0 + nbL) * 64 + ff) * 32 + q * 8;
            *(uint4*)&WhSw[dst] = *(const uint4*)&sT[ff * 80 + nbL * 32 + q * 8];
        }
    }
}

// ------------------------------------------------------------------
// k_attn: block = (bt, 64 rows), wave w owns rows w*16..+15, all 64 cols.
// Per 128-n chunk: issue coalesced B-chunk loads (16KB shared) -> compute
// in-register A fragments (exp work hides load latency) -> ds_write ->
// barrier -> 16 MFMA from LDS B -> barrier. A-layout & epilogue proven
// in round 3. m^_i = lrelu(r_i+maxC) >= row max (single pass, p~<=1).
// ------------------------------------------------------------------
__global__ __launch_bounds__(256, 3) void k_attn(
    const unsigned int* __restrict__ adjBits,
    const unsigned short* __restrict__ WhSw,
    const float* __restrict__ s1, const float* __restrict__ s2,
    const float* __restrict__ f1v, const float* __restrict__ f2v,
    float* __restrict__ out)
{
    __shared__ __align__(16) float sC[N];                 // 4 KB
    __shared__ __align__(16) unsigned short sB[8192];     // 16 KB B-chunk

    const int tid  = threadIdx.x;
    // XCD swizzle: xcd = blockIdx%8 heuristic; 6 bt per XCD -> B set fits L2
    const int xcd = blockIdx.x & 7;
    const int idx = blockIdx.x >> 3;          // 0..95
    const int bt  = xcd * 6 + (idx >> 4);
    const int i0  = (idx & 15) * 64;
    const int lane = tid & 63;
    const int w    = tid >> 6;
    const int q    = lane >> 4;               // k-quad
    const int m15  = lane & 15;               // A row / out col within tile

    for (int j = tid; j < N; j += 256) sC[j] = s2[bt * N + j] + f2v[j];
    __syncthreads();

    // wave max over c (bank-friendly: lane*4 stride)
    float mx = -1e30f;
#pragma unroll
    for (int t = 0; t < 4; ++t) {
        const float4 v = *(const float4*)&sC[t * 256 + lane * 4];
        mx = fmaxf(mx, fmaxf(fmaxf(v.x, v.y), fmaxf(v.z, v.w)));
    }
#pragma unroll
    for (int off = 32; off >= 1; off >>= 1) mx = fmaxf(mx, __shfl_xor(mx, off, 64));

    const int growq = i0 + w * 16 + m15;
    const float r   = s1[bt * N + growq] + f1v[growq];
    const float sm  = r + mx;
    const float mhat = (sm > 0.f) ? sm : LRELU_A * sm;
    float lsum = 0.f;

    const unsigned int* abRow = adjBits + growq * 32;
    const unsigned short* gBbt = WhSw + (size_t)bt * 65536;

    f32x4 acc[4];
#pragma unroll
    for (int ct = 0; ct < 4; ++ct)
#pragma unroll
        for (int e = 0; e < 4; ++e) acc[ct][e] = 0.f;

    for (int ch = 0; ch < 8; ++ch) {
        const int k0 = ch * 128;
        const unsigned short* gB = gBbt + ch * 8192;

        // B-chunk staging loads: coalesced, independent of everything below
        uint4 st[4];
#pragma unroll
        for (int k = 0; k < 4; ++k)
            st[k] = *(const uint4*)(gB + k * 2048 + tid * 8);

        const uint4 ab = *(const uint4*)&abRow[ch * 4];
        const unsigned int abw[4] = {ab.x, ab.y, ab.z, ab.w};

        // A fragments in registers (exp burst hides the staging latency)
        bf16x8 afr[4];
#pragma unroll
        for (int ks = 0; ks < 4; ++ks) {
            const float4 c0 = *(const float4*)&sC[k0 + ks * 32 + q * 8];
            const float4 c1 = *(const float4*)&sC[k0 + ks * 32 + q * 8 + 4];
            const float cj[8] = {c0.x, c0.y, c0.z, c0.w, c1.x, c1.y, c1.z, c1.w};
            const unsigned int mb = (abw[ks] >> (q * 8)) & 0xFFu;
            union { unsigned int u[4]; bf16x8 v; } A;
#pragma unroll
            for (int jp = 0; jp < 4; ++jp) {
                const float s0 = r + cj[2 * jp];
                const float s1v = r + cj[2 * jp + 1];
                const float e0 = (s0 > 0.f) ? s0 : LRELU_A * s0;
                const float e1 = (s1v > 0.f) ? s1v : LRELU_A * s1v;
                float p0 = __expf(e0 - mhat);
                float p1 = __expf(e1 - mhat);
                p0 = ((mb >> (2 * jp)) & 1u) ? p0 : 0.f;
                p1 = ((mb >> (2 * jp + 1)) & 1u) ? p1 : 0.f;
                lsum += p0 + p1;
                // pack two bf16 (bias-rounded) with one v_perm_b32
                A.u[jp] = __builtin_amdgcn_perm(
                    __float_as_uint(p1) + 0x8000u,
                    __float_as_uint(p0) + 0x8000u, 0x07060302u);
            }
            afr[ks] = A.v;
        }

        // commit staging to LDS (vmcnt waits land here, already drained by exp)
#pragma unroll
        for (int k = 0; k < 4; ++k)
            *(uint4*)((char*)sB + k * 4096 + tid * 16) = st[k];
        __syncthreads();

        // MFMA: B frags from LDS, ~min-cycle b128 reads
#pragma unroll
        for (int ct = 0; ct < 4; ++ct) {
#pragma unroll
            for (int ks = 0; ks < 4; ++ks) {
                const bf16x8 bfr = *(const bf16x8*)
                    ((const char*)sB + ks * 4096 + (ct * 16 + m15) * 64 + q * 16);
                acc[ct] = __builtin_amdgcn_mfma_f32_16x16x32_bf16(
                    afr[ks], bfr, acc[ct], 0, 0, 0);
            }
        }
        __syncthreads();
    }

    // row denominators: lanes {l, l^16, l^32, l^48} share row m15
    lsum += __shfl_xor(lsum, 16, 64);
    lsum += __shfl_xor(lsum, 32, 64);

    float rinv[4];
#pragma unroll
    for (int reg = 0; reg < 4; ++reg)
        rinv[reg] = 1.f / __shfl(lsum, q * 4 + reg, 64);

#pragma unroll
    for (int ct = 0; ct < 4; ++ct) {
#pragma unroll
        for (int reg = 0; reg < 4; ++reg) {
            float h = acc[ct][reg] * rinv[reg];
            h = (h > 0.f) ? h : (__expf(h) - 1.f);        // ELU
            out[(size_t)(bt * N + i0 + w * 16 + q * 4 + reg) * F + ct * 16 + m15] = h;
        }
    }
}

// ------------------------------------------------------------------
extern "C" void kernel_launch(void* const* d_in, const int* in_sizes, int n_in,
                              void* d_out, int out_size, void* d_ws, size_t ws_size,
                              hipStream_t stream)
{
    const float* x    = (const float*)d_in[0];
    const int*   adj  = (const int*)  d_in[1];
    const float* emb1 = (const float*)d_in[2];
    const float* emb2 = (const float*)d_in[3];
    const float* W    = (const float*)d_in[4];
    const float* a    = (const float*)d_in[5];
    const float* a2   = (const float*)d_in[6];
    float* out = (float*)d_out;

    unsigned short* WhSw = (unsigned short*)d_ws;             // 48*65536 bf16 = 6.29 MB
    float* s1 = (float*)(WhSw + (size_t)BT * 65536);          // 48K f32
    float* s2 = s1 + BT * N;
    float* f1 = s2 + BT * N;
    float* f2 = f1 + N;
    unsigned int* adjBits = (unsigned int*)(f2 + N);          // 128 KB

    hipLaunchKernelGGL(k_proj_misc, dim3(900), dim3(256), 0, stream,
                       x, W, a, adj, emb1, emb2, a2, WhSw, s1, s2, adjBits, f1, f2);
    hipLaunchKernelGGL(k_attn, dim3(BT * 16), dim3(256), 0, stream,
                       adjBits, WhSw, s1, s2, f1, f2, out);
}